// Round 2
// baseline (101.935 us; speedup 1.0000x reference)
//
#include <hip/hip_runtime.h>

// NeuralCA: out = clip(x + sum_k sigmoid(10*(conv3x3_k(x) - r_k)) * (p_k - x), 0, 1)
// B=16, H=W=512, NK=16, fp32.
//
// R6 theory: R0 (pk + VGPR consts, 4 w/SIMD) and R1 (pk + SGPR-pair consts,
// 8 w/SIMD) measured IDENTICAL kernel time (~40us vs ~10us issue floor) =>
// occupancy and source-level movs are not the lever. Prev-session counters said
// VALU-issue-bound at ~3cy/instr => emitted count is ~3x the source-level count.
// Blame: VOP3P pack/unpack churn -- exp/rcp are scalar-only, so every sigmoid
// unpacks the pk pair and repacks into even-aligned VGPR pairs, and VOP3P
// SGPR-pair operands get broadcast-mov'd. None of this is visible in source.
// Fix: ALL-SCALAR VOP3. v_fma_f32 takes one SGPR src directly, so raw weights
// s_load from kernargs feed the conv with zero movs and zero VGPR cost; the
// sigmoid chain is scalar end-to-end (subrev, mul-literal, exp, add-inline-1.0,
// rcp, subrev, fma) = 16 VALU per px-k, mov-free by construction.
// Single accumulator d += sig*(p_k - x) (8 regs, not 16). No prep kernel, no ws.
// Window 24 + acc 8 + temps ~16 => ~48 VGPR, __launch_bounds__(256,8):
// 2048 blocks = 32 waves/CU exactly, one residency pass.
// Prediction: kernel ~40 -> 17-22us, dur_us -> 64-72. If unchanged, instr count
// is not the lever (next: memory-latency structure).

#define NK 16
#define BATCH 16
#define H 512
#define W 512
#define G2 14.4269504088896340f   // GAIN(=10) * log2(e)

#if __has_builtin(__builtin_amdgcn_exp2f)
#define EXP2F(x) __builtin_amdgcn_exp2f(x)
#else
#define EXP2F(x) exp2f(x)
#endif

// Constant address space -> guaranteed s_load (SGPR broadcast; uniform index)
typedef const __attribute__((address_space(4))) float cfloat;

__global__ __launch_bounds__(256, 8) void nca_kernel(
    const float* __restrict__ x,
    const float* __restrict__ kernels,
    const float* __restrict__ reactants,
    const float* __restrict__ products,
    float* __restrict__ out)
{
    // One thread per 2x4 pixel tile. 16 * 256 * 128 = 2^19 threads, 2048 blocks.
    const int idx = blockIdx.x * blockDim.x + threadIdx.x;
    const int w4 = (idx & 127) << 2;        // tile start col (128 tiles/row)
    const int h0 = ((idx >> 7) & 255) << 1; // tile start row
    const int b  = idx >> 15;

    const float* xb = x + (size_t)b * (H * W);

    // 4 rows x 6 cols register window (rows h0-1 .. h0+2, halo 1 each side in w)
    float v[4][6];
#pragma unroll
    for (int r = 0; r < 4; ++r) {
        const int row = h0 + r - 1;
        if (row >= 0 && row < H) {
            const float* xr = xb + row * W;
            const float4 c = *(const float4*)(xr + w4);
            v[r][1] = c.x; v[r][2] = c.y; v[r][3] = c.z; v[r][4] = c.w;
            v[r][0] = (w4 > 0)     ? xr[w4 - 1] : 0.0f;   // zero pad left
            v[r][5] = (w4 + 4 < W) ? xr[w4 + 4] : 0.0f;   // zero pad right
        } else {
#pragma unroll
            for (int c = 0; c < 6; ++c) v[r][c] = 0.0f;   // zero pad top/bottom
        }
    }

    cfloat* kc = (cfloat*)kernels;
    cfloat* rc = (cfloat*)reactants;
    cfloat* pc = (cfloat*)products;

    // d[py][px] = sum_k sig_k * (p_k - x)   (single accumulator per pixel)
    float d[2][4];
#pragma unroll
    for (int py = 0; py < 2; ++py)
#pragma unroll
        for (int px = 0; px < 4; ++px) d[py][px] = 0.0f;

#pragma unroll
    for (int k = 0; k < NK; ++k) {
        // All uniform scalar loads -> SGPRs; consumed directly by VOP3 (1 sgpr src ok).
        float wk[9];
#pragma unroll
        for (int i = 0; i < 9; ++i) wk[i] = kc[k * 9 + i];
        const float rk = rc[k];
        const float pk = pc[k];

#pragma unroll
        for (int py = 0; py < 2; ++py) {
#pragma unroll
            for (int px = 0; px < 4; ++px) {
                float n = 0.0f;
#pragma unroll
                for (int r = 0; r < 3; ++r)
#pragma unroll
                    for (int c = 0; c < 3; ++c)
                        n = fmaf(v[py + r][px + c], wk[r * 3 + c], n); // 9 v_fma (sgpr wk)
                // sigmoid(10*(n-rk)) = 1 / (1 + 2^(G2*(rk-n)))
                const float z = (rk - n) * G2;         // v_subrev (sgpr rk) + v_mul (literal)
                const float e = EXP2F(z);              // v_exp_f32
                const float sig = __builtin_amdgcn_rcpf(e + 1.0f); // v_add (inline 1.0) + v_rcp
                d[py][px] = fmaf(sig, pk - v[py + 1][px + 1], d[py][px]); // v_subrev (sgpr pk) + v_fma
            }
        }
    }

#pragma unroll
    for (int py = 0; py < 2; ++py) {
        float4 o;
        float res[4];
#pragma unroll
        for (int px = 0; px < 4; ++px) {
            float r0 = v[py + 1][px + 1] + d[py][px];  // x + delta
            res[px] = fminf(fmaxf(r0, 0.0f), 1.0f);    // inline 0.0 / 1.0
        }
        o.x = res[0]; o.y = res[1]; o.z = res[2]; o.w = res[3];
        *(float4*)(out + ((size_t)(b * H + h0 + py) * W + w4)) = o;
    }
}

extern "C" void kernel_launch(void* const* d_in, const int* in_sizes, int n_in,
                              void* d_out, int out_size, void* d_ws, size_t ws_size,
                              hipStream_t stream) {
    const float* x         = (const float*)d_in[0];
    const float* kernels   = (const float*)d_in[1];
    const float* reactants = (const float*)d_in[2];
    const float* products  = (const float*)d_in[3];
    float* out = (float*)d_out;

    const int total_tiles = BATCH * (H / 2) * (W / 4);  // 2^19 threads
    nca_kernel<<<total_tiles / 256, 256, 0, stream>>>(x, kernels, reactants, products, out);
}

// Round 3
// 92.375 us; speedup vs baseline: 1.1035x; 1.1035x over previous
//
#include <hip/hip_runtime.h>

// NeuralCA: out = clip(x + sum_k sigmoid(10*(conv3x3_k(x) - r_k)) * (p_k - x), 0, 1)
// B=16, H=W=512, NK=16, fp32.
//
// R7: validated cost model from R0/R1/R2 (residual <0.2us):
//   dur_us = 77.8 + N_valu_per_thread * 0.0113
// where F=77.8 is fixed harness cost (ws-poison fill ~44 + out fill ~2.8 +
// ~28 gaps/tiny-memsets + ~3 kernel mem floor) and N is pk-weighted VALU per
// 2x4-tile thread (3.4 cy/instr effective across 8192 waves / 1024 SIMDs).
// R0 (pk, N~1190) = 91.3; R2 (scalar, N~2130) = 101.9; R1 (2x2 + prep launch)
// = 94.8 -- all predicted exactly. k-loop floor is 17 pk-ops/pixel-pair/k
// (9 conv + 1 z + 2 exp + 1 add + 2 rcp + 2 accum); Winograd, f16-dot2, and
// G2-prefolding all cost more than they save. This version = R0 structure with
// the only free trims: single accumulator (epilogue -1 pk/pair, -8 VGPR) and
// explicit v_med3 clamp (-1/px). Predicted 90.5-91.3us. If confirmed, this is
// the structural floor (controllable VALU ~13us of 91; rest is harness-fixed).

#define NK 16
#define BATCH 16
#define H 512
#define W 512
#define G2 14.4269504088896340f   // GAIN(=10) * log2(e)

typedef float f2 __attribute__((ext_vector_type(2)));

#if __has_builtin(__builtin_amdgcn_exp2f)
#define EXP2F(x) __builtin_amdgcn_exp2f(x)
#else
#define EXP2F(x) exp2f(x)
#endif

#if __has_builtin(__builtin_elementwise_fma)
#define FMA2(a, b, c) __builtin_elementwise_fma((a), (b), (c))
#else
#define FMA2(a, b, c) ((a) * (b) + (c))   // fp-contract=fast folds to fma.v2f32
#endif

static __device__ __forceinline__ f2 bc2(float s) { f2 r; r.x = s; r.y = s; return r; }

// Constant address space -> guaranteed s_load (SGPR broadcast)
typedef const __attribute__((address_space(4))) float cfloat;

__global__ __launch_bounds__(256, 4) void nca_kernel(
    const float* __restrict__ x,
    const float* __restrict__ kernels,
    const float* __restrict__ reactants,
    const float* __restrict__ products,
    float* __restrict__ out)
{
    // One thread per 2x4 pixel tile. Tiles: 16 * 256 * 128 = 2^19 threads.
    const int idx = blockIdx.x * blockDim.x + threadIdx.x;
    const int w4 = (idx & 127) << 2;        // tile start col (128 tiles/row)
    const int h0 = ((idx >> 7) & 255) << 1; // tile start row
    const int b  = idx >> 15;

    const float* xb = x + (size_t)b * (H * W);

    // 4 rows x 6 cols register window (rows h0-1 .. h0+2, halo 1 each side in w)
    float v[4][6];
#pragma unroll
    for (int r = 0; r < 4; ++r) {
        const int row = h0 + r - 1;
        if (row >= 0 && row < H) {
            const float* xr = xb + row * W;
            const float4 c = *(const float4*)(xr + w4);
            v[r][1] = c.x; v[r][2] = c.y; v[r][3] = c.z; v[r][4] = c.w;
            v[r][0] = (w4 > 0)     ? xr[w4 - 1] : 0.0f;   // zero pad left
            v[r][5] = (w4 + 4 < W) ? xr[w4 + 4] : 0.0f;   // zero pad right
        } else {
#pragma unroll
            for (int c = 0; c < 6; ++c) v[r][c] = 0.0f;   // zero pad top/bottom
        }
    }

    // Shifted float2 slices: sl[r][s] = {v[r][s], v[r][s+1]}, s = 0..4.
    // Built once, reused by all 16 kernels. Output pair g (local cols 2g,2g+1)
    // tap c uses sl[r][2g+c]; its center x pair is sl[py+1][2g+1].
    f2 sl[4][5];
#pragma unroll
    for (int r = 0; r < 4; ++r)
#pragma unroll
        for (int s = 0; s < 5; ++s) { sl[r][s].x = v[r][s]; sl[r][s].y = v[r][s + 1]; }

    cfloat* kc = (cfloat*)kernels;
    cfloat* rc = (cfloat*)reactants;
    cfloat* pc = (cfloat*)products;

    // Single accumulator: dd[py][g] = sum_k sig_k * (p_k - x)   (reference order)
    f2 dd[2][2];
#pragma unroll
    for (int py = 0; py < 2; ++py)
#pragma unroll
        for (int g = 0; g < 2; ++g) dd[py][g] = bc2(0.0f);

    const f2 mg2 = bc2(-G2);
    const f2 one = bc2(1.0f);

#pragma unroll
    for (int k = 0; k < NK; ++k) {
        f2 wk[9];
#pragma unroll
        for (int i = 0; i < 9; ++i) wk[i] = bc2(kc[k * 9 + i]);
        const f2 c2 = bc2(G2 * rc[k]);    // z = c2 - G2*N ; 2^z = exp(-10*(N-r_k))
        const f2 pk = bc2(pc[k]);

#pragma unroll
        for (int py = 0; py < 2; ++py) {
#pragma unroll
            for (int g = 0; g < 2; ++g) {
                f2 n = bc2(0.0f);
#pragma unroll
                for (int r = 0; r < 3; ++r)
#pragma unroll
                    for (int c = 0; c < 3; ++c)
                        n = FMA2(sl[py + r][2 * g + c], wk[r * 3 + c], n); // 9 pk fma
                const f2 z = FMA2(mg2, n, c2);          // 1 pk fma
                f2 e;
                e.x = EXP2F(z.x);                        // v_exp_f32 x2
                e.y = EXP2F(z.y);
                const f2 d = e + one;                    // 1 pk add
                f2 sig;
                sig.x = __builtin_amdgcn_rcpf(d.x);      // v_rcp_f32 x2
                sig.y = __builtin_amdgcn_rcpf(d.y);
                const f2 t = pk - sl[py + 1][2 * g + 1]; // 1 pk add (neg mod)
                dd[py][g] = FMA2(sig, t, dd[py][g]);     // 1 pk fma
            }
        }
    }

#pragma unroll
    for (int py = 0; py < 2; ++py) {
        float4 o;
#pragma unroll
        for (int g = 0; g < 2; ++g) {
            const f2 xv = sl[py + 1][2 * g + 1];         // center pixels of pair
            f2 res = xv + dd[py][g];                     // 1 pk add
#if __has_builtin(__builtin_amdgcn_fmed3f)
            res.x = __builtin_amdgcn_fmed3f(res.x, 0.0f, 1.0f);  // v_med3 clamp
            res.y = __builtin_amdgcn_fmed3f(res.y, 0.0f, 1.0f);
#else
            res.x = fminf(fmaxf(res.x, 0.0f), 1.0f);
            res.y = fminf(fmaxf(res.y, 0.0f), 1.0f);
#endif
            if (g == 0) { o.x = res.x; o.y = res.y; }
            else        { o.z = res.x; o.w = res.y; }
        }
        *(float4*)(out + ((size_t)(b * H + h0 + py) * W + w4)) = o;
    }
}

extern "C" void kernel_launch(void* const* d_in, const int* in_sizes, int n_in,
                              void* d_out, int out_size, void* d_ws, size_t ws_size,
                              hipStream_t stream) {
    const float* x         = (const float*)d_in[0];
    const float* kernels   = (const float*)d_in[1];
    const float* reactants = (const float*)d_in[2];
    const float* products  = (const float*)d_in[3];
    float* out = (float*)d_out;

    const int total_tiles = BATCH * (H / 2) * (W / 4);  // 2^19
    nca_kernel<<<total_tiles / 256, 256, 0, stream>>>(x, kernels, reactants, products, out);
}